// Round 5
// baseline (104.100 us; speedup 1.0000x reference)
//
#include <hip/hip_runtime.h>
#include <math.h>

// Problem constants (from reference setup_inputs): z_list (P,B,D) fp32
constexpr int P = 64, B = 512, D = 1024;
constexpr int D4 = D / 4;           // 256 float4 per row
constexpr int WAVES = 4;            // waves per block
constexpr int PC = P / WAVES;       // 16 p-rows per wave (8 pairs)
#define EPS 1e-8f

__device__ inline float wave_reduce_sum(float v) {
#pragma unroll
  for (int off = 1; off < 64; off <<= 1) v += __shfl_xor(v, off);
  return v;
}

__device__ inline float dot4(const float4& a, const float4& b) {
  return a.x * b.x + a.y * b.y + a.z * b.z + a.w * b.w;
}

// One block (4 waves) per b. Each wave streams 16 p-rows of z[:,b,:] as 8
// row-pairs (depth-1 prefetch, 2 interleaved norm-reduce chains). LDS
// combines the 4 waves; block normalizes mean row -> a4, then atomically
// accumulates a4 into Sfin, usum into Tfin, and usum.a4 into diagsum.
// Last block (semaphore) computes out = (S.T - diagsum)/count - 1.
__global__ __launch_bounds__(256) void k_fused(const float* __restrict__ z,
                                               float* __restrict__ Sfin,
                                               float* __restrict__ Tfin,
                                               float* __restrict__ diagsum,
                                               int* __restrict__ counter,
                                               float* __restrict__ out) {
  const int b = blockIdx.x;
  const int t = threadIdx.x;
  const int w = t >> 6;              // wave 0..3
  const int lane = t & 63;

  __shared__ float4 lds_zs[WAVES][D4];  // 16 KB
  __shared__ float4 lds_uu[WAVES][D4];  // 16 KB
  __shared__ float red[2 * WAVES];

  float4 zs[4], uu[4];
#pragma unroll
  for (int k = 0; k < 4; ++k) {
    zs[k] = make_float4(0.f, 0.f, 0.f, 0.f);
    uu[k] = make_float4(0.f, 0.f, 0.f, 0.f);
  }

  // wave w handles p = w*PC .. w*PC+PC-1, rows z[p][b][:]
  const size_t pstride = (size_t)B * D4;  // float4 stride between p's
  const float4* base = (const float4*)z + ((size_t)(w * PC) * B + b) * D4;

  float4 curA[4], curB[4];
#pragma unroll
  for (int k = 0; k < 4; ++k) {
    curA[k] = base[k * 64 + lane];
    curB[k] = base[pstride + k * 64 + lane];
  }

  for (int pr = 0; pr < PC / 2; ++pr) {
    float4 nxtA[4], nxtB[4];
    const bool more = (pr + 1 < PC / 2);
    if (more) {
      const float4* nA = base + (size_t)(2 * pr + 2) * pstride;
      const float4* nB = base + (size_t)(2 * pr + 3) * pstride;
#pragma unroll
      for (int k = 0; k < 4; ++k) {
        nxtA[k] = nA[k * 64 + lane];
        nxtB[k] = nB[k * 64 + lane];
      }
    }

    // two independent norm reductions, interleaved for ILP
    float ssA = 0.f, ssB = 0.f;
#pragma unroll
    for (int k = 0; k < 4; ++k) {
      ssA += dot4(curA[k], curA[k]);
      ssB += dot4(curB[k], curB[k]);
    }
#pragma unroll
    for (int off = 1; off < 64; off <<= 1) {
      ssA += __shfl_xor(ssA, off);
      ssB += __shfl_xor(ssB, off);
    }
    const float wA = 1.0f / fmaxf(sqrtf(ssA), EPS);
    const float wB = 1.0f / fmaxf(sqrtf(ssB), EPS);

#pragma unroll
    for (int k = 0; k < 4; ++k) {
      zs[k].x += curA[k].x + curB[k].x;
      zs[k].y += curA[k].y + curB[k].y;
      zs[k].z += curA[k].z + curB[k].z;
      zs[k].w += curA[k].w + curB[k].w;
      uu[k].x += wA * curA[k].x + wB * curB[k].x;
      uu[k].y += wA * curA[k].y + wB * curB[k].y;
      uu[k].z += wA * curA[k].z + wB * curB[k].z;
      uu[k].w += wA * curA[k].w + wB * curB[k].w;
    }
    if (more) {
#pragma unroll
      for (int k = 0; k < 4; ++k) {
        curA[k] = nxtA[k];
        curB[k] = nxtB[k];
      }
    }
  }

  // cross-wave combine: wave w's float4 index k*64+lane
#pragma unroll
  for (int k = 0; k < 4; ++k) {
    lds_zs[w][k * 64 + lane] = zs[k];
    lds_uu[w][k * 64 + lane] = uu[k];
  }
  __syncthreads();

  // thread t now owns float4 index t (d = 4t..4t+3)
  float4 zsum = make_float4(0.f, 0.f, 0.f, 0.f);
  float4 usum = make_float4(0.f, 0.f, 0.f, 0.f);
#pragma unroll
  for (int ww = 0; ww < WAVES; ++ww) {
    float4 a = lds_zs[ww][t];
    float4 u = lds_uu[ww][t];
    zsum.x += a.x; zsum.y += a.y; zsum.z += a.z; zsum.w += a.w;
    usum.x += u.x; usum.y += u.y; usum.z += u.z; usum.w += u.w;
  }

  // ||z_sum||^2 across the block, broadcast
  float ss = dot4(zsum, zsum);
  ss = wave_reduce_sum(ss);
  if (lane == 0) red[w] = ss;
  __syncthreads();
  ss = red[0] + red[1] + red[2] + red[3];

  // an = (z_sum/P)/max(||z_sum||/P, eps) = z_sum / max(||z_sum||, P*eps)
  const float inv = 1.0f / fmaxf(sqrtf(ss), (float)P * EPS);
  float4 a4 = make_float4(zsum.x * inv, zsum.y * inv, zsum.z * inv, zsum.w * inv);

  // accumulate S += a4, T += usum (device-scope atomics, pre-zeroed buffers)
  atomicAdd(&Sfin[4 * t + 0], a4.x);
  atomicAdd(&Sfin[4 * t + 1], a4.y);
  atomicAdd(&Sfin[4 * t + 2], a4.z);
  atomicAdd(&Sfin[4 * t + 3], a4.w);
  atomicAdd(&Tfin[4 * t + 0], usum.x);
  atomicAdd(&Tfin[4 * t + 1], usum.y);
  atomicAdd(&Tfin[4 * t + 2], usum.z);
  atomicAdd(&Tfin[4 * t + 3], usum.w);

  float dg = dot4(usum, a4);
  dg = wave_reduce_sum(dg);
  if (lane == 0) red[WAVES + w] = dg;
  __syncthreads();
  if (t == 0) {
    const float dtot = red[WAVES] + red[WAVES + 1] + red[WAVES + 2] + red[WAVES + 3];
    atomicAdd(diagsum, dtot);
  }

  // semaphore: last block to finish accumulation finalizes
  __threadfence();
  __syncthreads();
  __shared__ int is_last;
  if (t == 0) {
    int old = atomicAdd(counter, 1);
    is_last = (old == B - 1);
  }
  __syncthreads();
  if (!is_last) return;

  __threadfence();
  float local = 0.f;
#pragma unroll
  for (int k = 0; k < 4; ++k) {
    float sv = __hip_atomic_load(&Sfin[4 * t + k], __ATOMIC_RELAXED, __HIP_MEMORY_SCOPE_AGENT);
    float tv = __hip_atomic_load(&Tfin[4 * t + k], __ATOMIC_RELAXED, __HIP_MEMORY_SCOPE_AGENT);
    local += sv * tv;
  }
  local = wave_reduce_sum(local);
  __shared__ float red2[4];
  if (lane == 0) red2[w] = local;
  __syncthreads();
  if (t == 0) {
    const float dot = red2[0] + red2[1] + red2[2] + red2[3];
    const float dsum = __hip_atomic_load(diagsum, __ATOMIC_RELAXED, __HIP_MEMORY_SCOPE_AGENT);
    const float count = 64.0f * 512.0f * 511.0f;  // P*B*(B-1), exact in fp32
    out[0] = (dot - dsum) / count - 1.0f;
  }
}

extern "C" void kernel_launch(void* const* d_in, const int* in_sizes, int n_in,
                              void* d_out, int out_size, void* d_ws, size_t ws_size,
                              hipStream_t stream) {
  const float* z = (const float*)d_in[0];  // z_list (P,B,D); d_in[1] unused

  float* ws = (float*)d_ws;
  float* Sfin = ws;                 // D floats
  float* Tfin = Sfin + D;           // D floats
  float* diagsum = Tfin + D;        // 1 float
  int* counter = (int*)(diagsum + 1);

  // zero accumulators + semaphore (per replay; graph-capturable)
  hipMemsetAsync(d_ws, 0, (2 * D + 2) * sizeof(float), stream);
  k_fused<<<B, 256, 0, stream>>>(z, Sfin, Tfin, diagsum, counter, (float*)d_out);
}

// Round 6
// 37.116 us; speedup vs baseline: 2.8047x; 2.8047x over previous
//
#include <hip/hip_runtime.h>
#include <math.h>

// Problem constants (from reference setup_inputs): z_list (P,B,D) fp32
constexpr int P = 64, B = 512, D = 1024;
constexpr int D4 = D / 4;           // 256 float4 per row
constexpr int WAVES = 4;            // waves per block in main kernel
constexpr int PC = P / WAVES;       // 16 p-rows per wave
constexpr int QUADS = PC / 4;       // 4 quads of 4 rows
constexpr int K3B = 32;             // blocks in S/T partial-sum kernel
constexpr int BPB = B / K3B;        // 16 b's per K3 block
#define EPS 1e-8f

__device__ inline float wave_reduce_sum(float v) {
#pragma unroll
  for (int off = 1; off < 64; off <<= 1) v += __shfl_xor(v, off);
  return v;
}

__device__ inline float dot4(const float4& a, const float4& b) {
  return a.x * b.x + a.y * b.y + a.z * b.z + a.w * b.w;
}

// K_main: one block (4 waves) per b. Each wave streams 16 p-rows of z[:,b,:]
// as 4 row-QUADS, double-buffered in registers (16 KB in flight per wave
// while computing), 4 interleaved norm-reduce chains for ILP. LDS combines
// the 4 waves; block normalizes mean row -> an[b], writes Uv[b], diag[b].
__global__ __launch_bounds__(256) void k_main(const float* __restrict__ z,
                                              float* __restrict__ an,
                                              float* __restrict__ Uv,
                                              float* __restrict__ diag) {
  const int b = blockIdx.x;
  const int t = threadIdx.x;
  const int w = t >> 6;              // wave 0..3
  const int lane = t & 63;

  __shared__ float4 lds_zs[WAVES][D4];  // 16 KB
  __shared__ float4 lds_uu[WAVES][D4];  // 16 KB
  __shared__ float red[2 * WAVES];

  float4 zs[4], uu[4];
#pragma unroll
  for (int k = 0; k < 4; ++k) {
    zs[k] = make_float4(0.f, 0.f, 0.f, 0.f);
    uu[k] = make_float4(0.f, 0.f, 0.f, 0.f);
  }

  // wave w handles p = w*PC .. w*PC+PC-1, rows z[p][b][:]
  const size_t pstride = (size_t)B * D4;  // float4 stride between p's
  const float4* base = (const float4*)z + ((size_t)(w * PC) * B + b) * D4;

  // register double-buffer: buf[parity][r*4+k] = row r of quad, float4 k
  // fully unrolled loop -> all indices static -> stays in registers
  float4 buf[2][16];
#pragma unroll
  for (int r = 0; r < 4; ++r)
#pragma unroll
    for (int k = 0; k < 4; ++k)
      buf[0][4 * r + k] = base[(size_t)r * pstride + k * 64 + lane];

#pragma unroll
  for (int q = 0; q < QUADS; ++q) {
    const int cb = q & 1, nb = cb ^ 1;
    if (q + 1 < QUADS) {
      const float4* nbase = base + (size_t)((q + 1) * 4) * pstride;
#pragma unroll
      for (int r = 0; r < 4; ++r)
#pragma unroll
        for (int k = 0; k < 4; ++k)
          buf[nb][4 * r + k] = nbase[(size_t)r * pstride + k * 64 + lane];
    }

    // 4 independent norm reductions, interleaved for ILP
    float ss[4] = {0.f, 0.f, 0.f, 0.f};
#pragma unroll
    for (int r = 0; r < 4; ++r)
#pragma unroll
      for (int k = 0; k < 4; ++k)
        ss[r] += dot4(buf[cb][4 * r + k], buf[cb][4 * r + k]);
#pragma unroll
    for (int off = 1; off < 64; off <<= 1) {
#pragma unroll
      for (int r = 0; r < 4; ++r) ss[r] += __shfl_xor(ss[r], off);
    }
    float wgt[4];
#pragma unroll
    for (int r = 0; r < 4; ++r) wgt[r] = 1.0f / fmaxf(sqrtf(ss[r]), EPS);

#pragma unroll
    for (int k = 0; k < 4; ++k) {
#pragma unroll
      for (int r = 0; r < 4; ++r) {
        const float4 c = buf[cb][4 * r + k];
        zs[k].x += c.x; zs[k].y += c.y; zs[k].z += c.z; zs[k].w += c.w;
        uu[k].x += wgt[r] * c.x; uu[k].y += wgt[r] * c.y;
        uu[k].z += wgt[r] * c.z; uu[k].w += wgt[r] * c.w;
      }
    }
  }

  // cross-wave combine: wave w's float4 index k*64+lane
#pragma unroll
  for (int k = 0; k < 4; ++k) {
    lds_zs[w][k * 64 + lane] = zs[k];
    lds_uu[w][k * 64 + lane] = uu[k];
  }
  __syncthreads();

  // thread t now owns float4 index t (d = 4t..4t+3)
  float4 zsum = make_float4(0.f, 0.f, 0.f, 0.f);
  float4 usum = make_float4(0.f, 0.f, 0.f, 0.f);
#pragma unroll
  for (int ww = 0; ww < WAVES; ++ww) {
    float4 a = lds_zs[ww][t];
    float4 u = lds_uu[ww][t];
    zsum.x += a.x; zsum.y += a.y; zsum.z += a.z; zsum.w += a.w;
    usum.x += u.x; usum.y += u.y; usum.z += u.z; usum.w += u.w;
  }

  // ||z_sum||^2 across the block, broadcast
  float ss2 = dot4(zsum, zsum);
  ss2 = wave_reduce_sum(ss2);
  if (lane == 0) red[w] = ss2;
  __syncthreads();
  ss2 = red[0] + red[1] + red[2] + red[3];

  // an = (z_sum/P)/max(||z_sum||/P, eps) = z_sum / max(||z_sum||, P*eps)
  const float inv = 1.0f / fmaxf(sqrtf(ss2), (float)P * EPS);
  float4 a4 = make_float4(zsum.x * inv, zsum.y * inv, zsum.z * inv, zsum.w * inv);

  ((float4*)an)[(size_t)b * D4 + t] = a4;
  ((float4*)Uv)[(size_t)b * D4 + t] = usum;

  float dg = dot4(usum, a4);
  dg = wave_reduce_sum(dg);
  if (lane == 0) red[WAVES + w] = dg;
  __syncthreads();
  if (t == 0) diag[b] = red[WAVES] + red[WAVES + 1] + red[WAVES + 2] + red[WAVES + 3];
}

// K3: partial column-sums of an and Uv over b-chunks -> Spart/Tpart [K3B][D]
__global__ __launch_bounds__(256) void k3_colsum(const float* __restrict__ an,
                                                 const float* __restrict__ Uv,
                                                 float* __restrict__ Spart,
                                                 float* __restrict__ Tpart) {
  const int blk = blockIdx.x;
  const int t = threadIdx.x;
  float4 s = make_float4(0.f, 0.f, 0.f, 0.f);
  float4 tt = make_float4(0.f, 0.f, 0.f, 0.f);
#pragma unroll 4
  for (int i = 0; i < BPB; ++i) {
    const size_t b = (size_t)blk * BPB + i;
    float4 a = ((const float4*)an)[b * D4 + t];
    float4 u = ((const float4*)Uv)[b * D4 + t];
    s.x += a.x; s.y += a.y; s.z += a.z; s.w += a.w;
    tt.x += u.x; tt.y += u.y; tt.z += u.z; tt.w += u.w;
  }
  ((float4*)Spart)[(size_t)blk * D4 + t] = s;
  ((float4*)Tpart)[(size_t)blk * D4 + t] = tt;
}

// K4: final combine. S = sum Spart, T = sum Tpart, out = (S.T - sum diag)/count - 1
__global__ __launch_bounds__(256) void k4_final(const float* __restrict__ Spart,
                                                const float* __restrict__ Tpart,
                                                const float* __restrict__ diag,
                                                float* __restrict__ out) {
  const int t = threadIdx.x;
  __shared__ float red[4];
  float4 S = make_float4(0.f, 0.f, 0.f, 0.f);
  float4 T = make_float4(0.f, 0.f, 0.f, 0.f);
#pragma unroll 4
  for (int blk = 0; blk < K3B; ++blk) {
    float4 s = ((const float4*)Spart)[(size_t)blk * D4 + t];
    float4 u = ((const float4*)Tpart)[(size_t)blk * D4 + t];
    S.x += s.x; S.y += s.y; S.z += s.z; S.w += s.w;
    T.x += u.x; T.y += u.y; T.z += u.z; T.w += u.w;
  }
  float local = dot4(S, T) - diag[t] - diag[t + 256];
  local = wave_reduce_sum(local);
  const int wid = t >> 6;
  if ((t & 63) == 0) red[wid] = local;
  __syncthreads();
  if (t == 0) {
    const float tot = red[0] + red[1] + red[2] + red[3];
    const float count = 64.0f * 512.0f * 511.0f;  // P*B*(B-1), exact in fp32
    out[0] = tot / count - 1.0f;
  }
}

extern "C" void kernel_launch(void* const* d_in, const int* in_sizes, int n_in,
                              void* d_out, int out_size, void* d_ws, size_t ws_size,
                              hipStream_t stream) {
  const float* z = (const float*)d_in[0];  // z_list (P,B,D); d_in[1] unused

  float* ws = (float*)d_ws;
  float* an = ws;                                  // B*D
  float* Uv = an + (size_t)B * D;                  // B*D
  float* diag = Uv + (size_t)B * D;                // B
  float* Spart = diag + B;                         // K3B*D
  float* Tpart = Spart + (size_t)K3B * D;          // K3B*D

  k_main<<<B, 256, 0, stream>>>(z, an, Uv, diag);
  k3_colsum<<<K3B, 256, 0, stream>>>(an, Uv, Spart, Tpart);
  k4_final<<<1, 256, 0, stream>>>(Spart, Tpart, diag, (float*)d_out);
}